// Round 2
// baseline (1123.074 us; speedup 1.0000x reference)
//
#include <hip/hip_runtime.h>

// Problem constants
#define B_SZ   2
#define S_LEN  2048
#define DMODEL 1024
#define HID    256
#define NH     4
#define DH     64
#define DFF    512
#define LN_EPS 1e-5f
// scale = 1/sqrt(HID) = 1/16
#define ATT_SCALE 0.0625f

// ---------------------------------------------------------------------------
// Generic tiled fp32 GEMM: C[M,N] = act( A[M,K] @ W[K,N] + bias + resid )
// Optional inv_nrm: A element (m,k) scaled by inv_nrm[(m / S_LEN)*K + k]
// BM=BN=64, BK=16, 256 threads, 4x4 per-thread microtile.
// M,N multiples of 64; K multiple of 16 (true for all call sites).
// ---------------------------------------------------------------------------
__global__ __launch_bounds__(256) void gemm64(
    const float* __restrict__ A, const float* __restrict__ W,
    const float* __restrict__ bias, const float* __restrict__ resid,
    const float* __restrict__ inv_nrm, float* __restrict__ C,
    int M, int N, int K, int relu)
{
    __shared__ float As[16][65];
    __shared__ float Bs[16][65];
    const int row0 = blockIdx.x * 64;
    const int col0 = blockIdx.y * 64;
    const int t  = threadIdx.x;
    const int tx = t & 15, ty = t >> 4;

    float acc[4][4] = {};

    for (int k0 = 0; k0 < K; k0 += 16) {
        #pragma unroll
        for (int i = 0; i < 4; ++i) {
            int idx = t + i * 256;
            int m  = idx >> 4, kk = idx & 15;
            float a = A[(size_t)(row0 + m) * K + (k0 + kk)];
            if (inv_nrm) a *= inv_nrm[((row0 + m) / S_LEN) * K + (k0 + kk)];
            As[kk][m] = a;
            int kk2 = idx >> 6, n = idx & 63;
            Bs[kk2][n] = W[(size_t)(k0 + kk2) * N + (col0 + n)];
        }
        __syncthreads();
        #pragma unroll
        for (int kk = 0; kk < 16; ++kk) {
            float av[4], bv[4];
            #pragma unroll
            for (int i = 0; i < 4; ++i) av[i] = As[kk][ty * 4 + i];
            #pragma unroll
            for (int j = 0; j < 4; ++j) bv[j] = Bs[kk][tx * 4 + j];
            #pragma unroll
            for (int i = 0; i < 4; ++i)
                #pragma unroll
                for (int j = 0; j < 4; ++j)
                    acc[i][j] += av[i] * bv[j];
        }
        __syncthreads();
    }

    #pragma unroll
    for (int i = 0; i < 4; ++i) {
        int r = row0 + ty * 4 + i;
        #pragma unroll
        for (int j = 0; j < 4; ++j) {
            int c = col0 + tx * 4 + j;
            float v2 = acc[i][j] + bias[c];
            if (resid) v2 += resid[(size_t)r * N + c];
            if (relu)  v2 = fmaxf(v2, 0.f);
            C[(size_t)r * N + c] = v2;
        }
    }
}

// ---------------------------------------------------------------------------
// Global attention, flash-style online softmax.
// Q/K/V projected layout: [B, S, HID] with head h occupying cols h*64..h*64+63.
// Output glb layout: [B, S, H, DH]  (== [B,S,HID] channel = h*64+d)
// grid = (S/64, B*H), block = 256 (16x16 threads, 4x4 scores each)
// ---------------------------------------------------------------------------
__global__ __launch_bounds__(256) void attn_global(
    const float* __restrict__ Qp, const float* __restrict__ Kp,
    const float* __restrict__ Vp, const float* __restrict__ adj_w,
    const float* __restrict__ adj_b, float* __restrict__ glb)
{
    __shared__ float Qs[64][65];
    __shared__ float Ks[64][65];
    __shared__ float Vs[64][65];
    __shared__ float Ps[64][65];

    const int q0 = blockIdx.x * 64;
    const int bh = blockIdx.y;
    const int b = bh / NH, h = bh % NH;
    const int t = threadIdx.x;
    const int tx = t & 15, ty = t >> 4;
    const float w = adj_w[0], bb = adj_b[0];

    // load Q tile [64 rows x 64 dh]
    #pragma unroll
    for (int i = 0; i < 16; ++i) {
        int idx = t + i * 256;
        int r = idx >> 6, d = idx & 63;
        Qs[r][d] = Qp[((size_t)(b * S_LEN + q0 + r) * HID) + h * 64 + d];
    }

    float m[4], l[4] = {0.f, 0.f, 0.f, 0.f};
    float O[4][4] = {};
    #pragma unroll
    for (int i = 0; i < 4; ++i) m[i] = -1e30f;

    for (int k0 = 0; k0 < S_LEN; k0 += 64) {
        __syncthreads();
        #pragma unroll
        for (int i = 0; i < 16; ++i) {
            int idx = t + i * 256;
            int r = idx >> 6, d = idx & 63;
            Ks[r][d] = Kp[((size_t)(b * S_LEN + k0 + r) * HID) + h * 64 + d];
            Vs[r][d] = Vp[((size_t)(b * S_LEN + k0 + r) * HID) + h * 64 + d];
        }
        __syncthreads();

        // scores 4x4
        float s[4][4] = {};
        for (int d = 0; d < 64; ++d) {
            float av[4], bv[4];
            #pragma unroll
            for (int i = 0; i < 4; ++i) av[i] = Qs[ty * 4 + i][d];
            #pragma unroll
            for (int j = 0; j < 4; ++j) bv[j] = Ks[tx * 4 + j][d];
            #pragma unroll
            for (int i = 0; i < 4; ++i)
                #pragma unroll
                for (int j = 0; j < 4; ++j)
                    s[i][j] += av[i] * bv[j];
        }
        #pragma unroll
        for (int i = 0; i < 4; ++i) {
            int gi = q0 + ty * 4 + i;
            #pragma unroll
            for (int j = 0; j < 4; ++j) {
                int gj = k0 + tx * 4 + j;
                float dd = fabsf((float)(gi - gj));
                s[i][j] = s[i][j] * ATT_SCALE + expf(-fabsf(w * dd * dd - bb));
            }
        }

        // row-wise tile max across the 16 tx-threads
        float tm[4];
        #pragma unroll
        for (int i = 0; i < 4; ++i)
            tm[i] = fmaxf(fmaxf(s[i][0], s[i][1]), fmaxf(s[i][2], s[i][3]));
        #pragma unroll
        for (int off = 1; off < 16; off <<= 1) {
            #pragma unroll
            for (int i = 0; i < 4; ++i)
                tm[i] = fmaxf(tm[i], __shfl_xor(tm[i], off, 64));
        }

        float f[4], ts[4];
        #pragma unroll
        for (int i = 0; i < 4; ++i) {
            float mn = fmaxf(m[i], tm[i]);
            f[i] = expf(m[i] - mn);
            m[i] = mn;
            ts[i] = 0.f;
        }
        #pragma unroll
        for (int i = 0; i < 4; ++i)
            #pragma unroll
            for (int j = 0; j < 4; ++j) {
                s[i][j] = expf(s[i][j] - m[i]);
                ts[i] += s[i][j];
            }
        #pragma unroll
        for (int off = 1; off < 16; off <<= 1) {
            #pragma unroll
            for (int i = 0; i < 4; ++i)
                ts[i] += __shfl_xor(ts[i], off, 64);
        }
        #pragma unroll
        for (int i = 0; i < 4; ++i) {
            l[i] = l[i] * f[i] + ts[i];
            #pragma unroll
            for (int j = 0; j < 4; ++j) O[i][j] *= f[i];
        }

        // write P tile, then PV accumulate
        #pragma unroll
        for (int i = 0; i < 4; ++i)
            #pragma unroll
            for (int j = 0; j < 4; ++j)
                Ps[ty * 4 + i][tx * 4 + j] = s[i][j];
        __syncthreads();

        for (int jj = 0; jj < 64; ++jj) {
            float pv[4], vv[4];
            #pragma unroll
            for (int i = 0; i < 4; ++i) pv[i] = Ps[ty * 4 + i][jj];
            #pragma unroll
            for (int j = 0; j < 4; ++j) vv[j] = Vs[jj][tx * 4 + j];
            #pragma unroll
            for (int i = 0; i < 4; ++i)
                #pragma unroll
                for (int j = 0; j < 4; ++j)
                    O[i][j] += pv[i] * vv[j];
        }
    }

    #pragma unroll
    for (int i = 0; i < 4; ++i) {
        float inv = 1.f / l[i];
        int r = q0 + ty * 4 + i;
        #pragma unroll
        for (int j = 0; j < 4; ++j) {
            int d = tx * 4 + j;
            glb[(((size_t)(b * S_LEN + r)) * NH + h) * DH + d] = O[i][j] * inv;
        }
    }
}

// ---------------------------------------------------------------------------
// Local windowed attention (WIN=9, clipped indices dedup'd).
// One wave per (b,h,row). block = 256 => 4 rows/block.
// ---------------------------------------------------------------------------
__global__ __launch_bounds__(256) void attn_local(
    const float* __restrict__ Qp, const float* __restrict__ Kp,
    const float* __restrict__ Vp, const float* __restrict__ adj_w,
    const float* __restrict__ adj_b, float* __restrict__ lcl)
{
    const int wave = threadIdx.x >> 6;
    const int lane = threadIdx.x & 63;
    const int gr = blockIdx.x * 4 + wave;   // 0 .. B*H*S-1
    const int b = gr >> 13;                 // / (H*S) = 8192
    const int rem = gr & 8191;
    const int h = rem >> 11;                // / S
    const int i = rem & 2047;
    const float w = adj_w[0], bb = adj_b[0];

    const float qd = Qp[((size_t)(b * S_LEN + i) * HID) + h * 64 + lane];

    float sc[9];
    int   cls[9];
    float mx = -1e30f;
    int prev = -1;
    #pragma unroll
    for (int kk = 0; kk < 9; ++kk) {
        int c = i - 4 + kk;
        c = c < 0 ? 0 : (c > S_LEN - 1 ? S_LEN - 1 : c);
        bool valid = (c != prev);
        prev = c;
        float kd = Kp[((size_t)(b * S_LEN + c) * HID) + h * 64 + lane];
        float part = qd * kd;
        #pragma unroll
        for (int off = 32; off; off >>= 1) part += __shfl_xor(part, off, 64);
        float dd = fabsf((float)(i - c));
        float v = part * ATT_SCALE + expf(-fabsf(w * dd * dd - bb));
        sc[kk]  = valid ? v : -1e30f;
        cls[kk] = c;
        mx = fmaxf(mx, sc[kk]);
    }
    float sum = 0.f;
    #pragma unroll
    for (int kk = 0; kk < 9; ++kk) {
        sc[kk] = expf(sc[kk] - mx);   // invalid -> exp(-huge) = 0
        sum += sc[kk];
    }
    const float inv = 1.f / sum;
    float o = 0.f;
    #pragma unroll
    for (int kk = 0; kk < 9; ++kk)
        o += sc[kk] * Vp[((size_t)(b * S_LEN + cls[kk]) * HID) + h * 64 + lane];

    lcl[(((size_t)(b * S_LEN + i)) * NH + h) * DH + lane] = o * inv;
}

// ---------------------------------------------------------------------------
// tmp = sigmoid(alpha)*glb + (1-sigmoid)*lcl ; signed sqrt. In-place over glb.
// ---------------------------------------------------------------------------
__global__ void combine_ss(const float* g, const float* l,
                           const float* alpha, float* out, int n)
{
    const float a = 1.f / (1.f + expf(-alpha[0]));
    for (int idx = blockIdx.x * blockDim.x + threadIdx.x; idx < n;
         idx += gridDim.x * blockDim.x) {
        float x = a * g[idx] + (1.f - a) * l[idx];
        float r = x > 0.f ? sqrtf(x) : (x < 0.f ? -sqrtf(-x) : 0.f);
        out[idx] = r;
    }
}

// ---------------------------------------------------------------------------
// inv_nrm[b*HID+c] = 1 / max(sqrt(sum_s tmp[b,s,c]^2), 1e-12)
// grid = B*HID blocks of 256 threads.
// ---------------------------------------------------------------------------
__global__ __launch_bounds__(256) void colnorm_kernel(
    const float* __restrict__ tmp, float* __restrict__ inv_nrm)
{
    const int bc = blockIdx.x;
    const int b = bc >> 8, c = bc & 255;
    const float* base = tmp + (size_t)b * S_LEN * HID + c;
    float ss = 0.f;
    for (int s = threadIdx.x; s < S_LEN; s += 256) {
        float v = base[(size_t)s * HID];
        ss += v * v;
    }
    #pragma unroll
    for (int off = 32; off; off >>= 1) ss += __shfl_xor(ss, off, 64);
    __shared__ float red[4];
    if ((threadIdx.x & 63) == 0) red[threadIdx.x >> 6] = ss;
    __syncthreads();
    if (threadIdx.x == 0) {
        float t = red[0] + red[1] + red[2] + red[3];
        inv_nrm[bc] = 1.f / fmaxf(sqrtf(t), 1e-12f);
    }
}

// ---------------------------------------------------------------------------
// LayerNorm over last dim (1024). One block per row, float4 per thread.
// ---------------------------------------------------------------------------
__global__ __launch_bounds__(256) void layernorm_k(
    const float* __restrict__ x, const float* __restrict__ g,
    const float* __restrict__ be, float* __restrict__ out)
{
    const int row = blockIdx.x;
    const float4 xv = reinterpret_cast<const float4*>(x + (size_t)row * DMODEL)[threadIdx.x];
    float s  = xv.x + xv.y + xv.z + xv.w;
    float ss = xv.x * xv.x + xv.y * xv.y + xv.z * xv.z + xv.w * xv.w;
    #pragma unroll
    for (int off = 32; off; off >>= 1) {
        s  += __shfl_xor(s,  off, 64);
        ss += __shfl_xor(ss, off, 64);
    }
    __shared__ float rs[4], rss[4];
    if ((threadIdx.x & 63) == 0) { rs[threadIdx.x >> 6] = s; rss[threadIdx.x >> 6] = ss; }
    __syncthreads();
    s  = rs[0] + rs[1] + rs[2] + rs[3];
    ss = rss[0] + rss[1] + rss[2] + rss[3];
    const float mu  = s * (1.f / DMODEL);
    const float var = ss * (1.f / DMODEL) - mu * mu;
    const float r   = rsqrtf(var + LN_EPS);
    const float4 gv  = reinterpret_cast<const float4*>(g)[threadIdx.x];
    const float4 bv  = reinterpret_cast<const float4*>(be)[threadIdx.x];
    float4 ov;
    ov.x = (xv.x - mu) * r * gv.x + bv.x;
    ov.y = (xv.y - mu) * r * gv.y + bv.y;
    ov.z = (xv.z - mu) * r * gv.z + bv.z;
    ov.w = (xv.w - mu) * r * gv.w + bv.w;
    reinterpret_cast<float4*>(out + (size_t)row * DMODEL)[threadIdx.x] = ov;
}

// ---------------------------------------------------------------------------
extern "C" void kernel_launch(void* const* d_in, const int* in_sizes, int n_in,
                              void* d_out, int out_size, void* d_ws, size_t ws_size,
                              hipStream_t stream)
{
    const float* q     = (const float*)d_in[0];
    const float* k     = (const float*)d_in[1];
    const float* v     = (const float*)d_in[2];
    const float* Wq    = (const float*)d_in[3];
    const float* bq    = (const float*)d_in[4];
    const float* Wk    = (const float*)d_in[5];
    const float* bk    = (const float*)d_in[6];
    const float* Wv    = (const float*)d_in[7];
    const float* bv    = (const float*)d_in[8];
    const float* Wo    = (const float*)d_in[9];
    const float* bo    = (const float*)d_in[10];
    const float* alpha = (const float*)d_in[11];
    const float* adj_w = (const float*)d_in[12];
    const float* adj_b = (const float*)d_in[13];
    const float* W1    = (const float*)d_in[14];
    const float* b1    = (const float*)d_in[15];
    const float* W2    = (const float*)d_in[16];
    const float* b2    = (const float*)d_in[17];
    const float* g1    = (const float*)d_in[18];
    const float* be1   = (const float*)d_in[19];
    const float* g2    = (const float*)d_in[20];
    const float* be2   = (const float*)d_in[21];

    const int ROWS = B_SZ * S_LEN;         // 4096
    const size_t PROJ = (size_t)ROWS * HID; // 1,048,576 floats

    float* ws = (float*)d_ws;
    float* Qp      = ws;              // PROJ
    float* Kp      = Qp + PROJ;       // PROJ
    float* Vp      = Kp + PROJ;       // PROJ
    float* lcl     = Vp + PROJ;       // PROJ
    float* glb     = lcl + PROJ;      // PROJ (also tmp, in-place)
    float* inv_nrm = glb + PROJ;      // 512
    float* x_ln    = inv_nrm + 512;               // ROWS*DMODEL
    float* hbuf    = x_ln + (size_t)ROWS * DMODEL; // ROWS*DFF
    float* x1      = Qp;  // alias: Qp..lcl region = exactly ROWS*DMODEL floats

    dim3 blk(256);

    // QKV projections
    gemm64<<<dim3(64, 4), blk, 0, stream>>>(q, Wq, bq, nullptr, nullptr, Qp, ROWS, HID, DMODEL, 0);
    gemm64<<<dim3(64, 4), blk, 0, stream>>>(k, Wk, bk, nullptr, nullptr, Kp, ROWS, HID, DMODEL, 0);
    gemm64<<<dim3(64, 4), blk, 0, stream>>>(v, Wv, bv, nullptr, nullptr, Vp, ROWS, HID, DMODEL, 0);

    // attention
    attn_global<<<dim3(S_LEN / 64, B_SZ * NH), blk, 0, stream>>>(Qp, Kp, Vp, adj_w, adj_b, glb);
    attn_local<<<dim3(B_SZ * NH * S_LEN / 4), blk, 0, stream>>>(Qp, Kp, Vp, adj_w, adj_b, lcl);

    // combine + signed sqrt (in-place over glb)
    combine_ss<<<dim3(1024), blk, 0, stream>>>(glb, lcl, alpha, glb, (int)PROJ);

    // L2 norm over sequence axis -> inv_nrm
    colnorm_kernel<<<dim3(B_SZ * HID), blk, 0, stream>>>(glb, inv_nrm);

    // attn_out = (tmp/nrm) @ Wo + bo + q   -> x1
    gemm64<<<dim3(64, 16), blk, 0, stream>>>(glb, Wo, bo, q, inv_nrm, x1, ROWS, DMODEL, HID, 0);

    // LN1
    layernorm_k<<<dim3(ROWS), blk, 0, stream>>>(x1, g1, be1, x_ln);

    // FFN
    gemm64<<<dim3(64, 8),  blk, 0, stream>>>(x_ln, W1, b1, nullptr, nullptr, hbuf, ROWS, DFF, DMODEL, 1);
    gemm64<<<dim3(64, 16), blk, 0, stream>>>(hbuf, W2, b2, x_ln, nullptr, x1, ROWS, DMODEL, DFF, 0);

    // LN2 -> output
    layernorm_k<<<dim3(ROWS), blk, 0, stream>>>(x1, g2, be2, (float*)d_out);
}

// Round 3
// 427.042 us; speedup vs baseline: 2.6299x; 2.6299x over previous
//
#include <hip/hip_runtime.h>

// Problem constants
#define B_SZ   2
#define S_LEN  2048
#define DMODEL 1024
#define HID    256
#define NH     4
#define DH     64
#define DFF    512
#define LN_EPS 1e-5f
#define ATT_SCALE 0.0625f   // 1/sqrt(HID)

typedef __attribute__((ext_vector_type(8))) short bf16x8;
typedef __attribute__((ext_vector_type(4))) float f32x4;

// fp32 -> bf16 RNE
static __device__ __forceinline__ unsigned short f2bf(float x) {
    union { float f; unsigned u; } v; v.f = x;
    unsigned r = v.u + 0x7FFFu + ((v.u >> 16) & 1u);
    return (unsigned short)(r >> 16);
}
static __device__ __forceinline__ unsigned packbf(float a, float b) {
    return (unsigned)f2bf(a) | ((unsigned)f2bf(b) << 16);
}
// LDS XOR swizzle: flip byte bits 4-6 with bits 7-9. Involution, applied on
// both write and read sides. Spreads 128B-stride (and 64B-stride) row
// accesses across banks (<=2-way aliasing = free).
static __device__ __forceinline__ int swz(int byte) {
    return byte ^ ((byte >> 3) & 0x70);
}

// ---------------------------------------------------------------------------
// MFMA bf16 GEMM core: C[M,N] = act(A[M,K]@W[K,N] + bias (+resid)), optional
// per-column-of-A scale inv_nrm[(row/S_LEN)*K + k]. Tile 128x128, BK=32,
// 256 threads = 4 waves (2x2), each wave 64x64 via 4x4 frags of 16x16x32.
// ---------------------------------------------------------------------------
__device__ __forceinline__ void gemm_core(
    const float* __restrict__ A, const float* __restrict__ W,
    const float* __restrict__ bias, const float* __restrict__ resid,
    const float* __restrict__ inv_nrm, float* __restrict__ C,
    int N, int K, int relu, int row0, int col0,
    unsigned* As, unsigned* Bs)
{
    const int t  = threadIdx.x;
    const int l  = t & 63;
    const int wv = t >> 6;
    const int wr = wv >> 1, wc = wv & 1;
    const int lr = l & 15,  lg = l >> 4;

    f32x4 acc[4][4] = {};

    for (int k0 = 0; k0 < K; k0 += 32) {
        __syncthreads();
        // stage A tile [128m][32k] fp32 -> bf16 swizzled (8 u32/thread)
        #pragma unroll
        for (int i = 0; i < 8; ++i) {
            int id = t + i * 256;          // 0..2047 u32 units
            int m = id >> 4, kp = id & 15, kk = kp * 2;
            const float* ap = A + (size_t)(row0 + m) * K + k0 + kk;
            float a0 = ap[0], a1 = ap[1];
            if (inv_nrm) {
                const float* ip = inv_nrm + ((row0 + m) / S_LEN) * K + k0 + kk;
                a0 *= ip[0]; a1 *= ip[1];
            }
            As[swz(m * 64 + kk * 2) >> 2] = packbf(a0, a1);
        }
        // stage W^T tile [128n][32k] fp32 -> bf16 swizzled
        #pragma unroll
        for (int i = 0; i < 8; ++i) {
            int id = t + i * 256;
            int n = id & 127, kp = id >> 7, kk = kp * 2;
            float b0 = W[(size_t)(k0 + kk)     * N + col0 + n];
            float b1 = W[(size_t)(k0 + kk + 1) * N + col0 + n];
            Bs[swz(n * 64 + kk * 2) >> 2] = packbf(b0, b1);
        }
        __syncthreads();

        bf16x8 afr[4], bfr[4];
        #pragma unroll
        for (int mf = 0; mf < 4; ++mf) {
            int row = wr * 64 + mf * 16 + lr;
            afr[mf] = *reinterpret_cast<const bf16x8*>(
                (const char*)As + swz(row * 64 + lg * 16));
        }
        #pragma unroll
        for (int nf = 0; nf < 4; ++nf) {
            int row = wc * 64 + nf * 16 + lr;
            bfr[nf] = *reinterpret_cast<const bf16x8*>(
                (const char*)Bs + swz(row * 64 + lg * 16));
        }
        #pragma unroll
        for (int mf = 0; mf < 4; ++mf)
            #pragma unroll
            for (int nf = 0; nf < 4; ++nf)
                acc[mf][nf] = __builtin_amdgcn_mfma_f32_16x16x32_bf16(
                    afr[mf], bfr[nf], acc[mf][nf], 0, 0, 0);
    }

    // epilogue: C row = (lane>>4)*4+reg, col = lane&15  (m89-verified layout)
    #pragma unroll
    for (int mf = 0; mf < 4; ++mf) {
        #pragma unroll
        for (int nf = 0; nf < 4; ++nf) {
            #pragma unroll
            for (int r = 0; r < 4; ++r) {
                int row = row0 + wr * 64 + mf * 16 + lg * 4 + r;
                int col = col0 + wc * 64 + nf * 16 + lr;
                float v2 = acc[mf][nf][r] + bias[col];
                if (resid) v2 += resid[(size_t)row * N + col];
                if (relu)  v2 = fmaxf(v2, 0.f);
                C[(size_t)row * N + col] = v2;
            }
        }
    }
}

__global__ __launch_bounds__(256) void gemm_mfma(
    const float* __restrict__ A, const float* __restrict__ W,
    const float* __restrict__ bias, const float* __restrict__ resid,
    const float* __restrict__ inv_nrm, float* __restrict__ C, int N, int K, int relu)
{
    __shared__ unsigned As[2048], Bs[2048];
    gemm_core(A, W, bias, resid, inv_nrm, C, N, K, relu,
              blockIdx.x * 128, blockIdx.y * 128, As, Bs);
}

// QKV fused as gridDim.z = 3 (fills CUs: 192 blocks vs 3x64)
__global__ __launch_bounds__(256) void gemm_qkv(
    const float* __restrict__ q, const float* __restrict__ k, const float* __restrict__ v,
    const float* __restrict__ Wq, const float* __restrict__ Wk, const float* __restrict__ Wv,
    const float* __restrict__ bq, const float* __restrict__ bk, const float* __restrict__ bv,
    float* __restrict__ Qp, float* __restrict__ Kp, float* __restrict__ Vp)
{
    __shared__ unsigned As[2048], Bs[2048];
    const float *A, *W, *bi; float* C;
    if (blockIdx.z == 0)      { A = q; W = Wq; bi = bq; C = Qp; }
    else if (blockIdx.z == 1) { A = k; W = Wk; bi = bk; C = Kp; }
    else                      { A = v; W = Wv; bi = bv; C = Vp; }
    gemm_core(A, W, bi, nullptr, nullptr, C, HID, DMODEL, 0,
              blockIdx.x * 128, blockIdx.y * 128, As, Bs);
}

// ---------------------------------------------------------------------------
// prep: Kp,Vp fp32 [B,S,HID] -> Kb bf16 [bh][S][64], Vt bf16 [bh][64][S]
// grid (S/64, B*NH), 256 threads
// ---------------------------------------------------------------------------
__global__ __launch_bounds__(256) void prep_kv(
    const float* __restrict__ Kp, const float* __restrict__ Vp,
    unsigned short* __restrict__ Kb, unsigned short* __restrict__ Vt)
{
    __shared__ float Vf[64][65];
    const int k0 = blockIdx.x * 64;
    const int bh = blockIdx.y;
    const int b = bh >> 2, h = bh & 3;
    const int t = threadIdx.x;

    unsigned* Kb32 = reinterpret_cast<unsigned*>(Kb + (size_t)bh * S_LEN * DH);
    #pragma unroll
    for (int i = 0; i < 8; ++i) {
        int id = t + i * 256;           // 0..2047
        int key = id >> 5, dp = id & 31, d = dp * 2;
        const float* kp2 = Kp + (size_t)(b * S_LEN + k0 + key) * HID + h * 64 + d;
        Kb32[(size_t)(k0 + key) * 32 + dp] = packbf(kp2[0], kp2[1]);
        const float* vp2 = Vp + (size_t)(b * S_LEN + k0 + key) * HID + h * 64 + d;
        Vf[key][d] = vp2[0]; Vf[key][d + 1] = vp2[1];
    }
    __syncthreads();
    unsigned* Vt32 = reinterpret_cast<unsigned*>(Vt + (size_t)bh * DH * S_LEN);
    #pragma unroll
    for (int i = 0; i < 8; ++i) {
        int id = t + i * 256;           // 0..2047
        int d = id >> 5, kp = id & 31, key = kp * 2;
        Vt32[(size_t)d * (S_LEN / 2) + ((k0 + key) >> 1)] =
            packbf(Vf[key][d], Vf[key + 1][d]);
    }
}

// ---------------------------------------------------------------------------
// Global attention, MFMA flash. grid (S/64, B*NH), 256 thr = 4 waves.
// Wave w owns q-rows [q0+16w, q0+16w+16). K-tile = 64 keys.
// S^T = mfma(K, Q)  -> lane holds one q-row (col=lane&15), 16 keys.
// O^T = mfma(V^T, P^T) -> lane holds one q-row, 16 dh.
// ---------------------------------------------------------------------------
__global__ __launch_bounds__(256) void attn_global_mfma(
    const float* __restrict__ Qp, const unsigned short* __restrict__ Kb,
    const unsigned short* __restrict__ Vt, const float* __restrict__ adj_w,
    const float* __restrict__ adj_b, float* __restrict__ glb)
{
    __shared__ unsigned Kl[2048];        // [key64][dh64] bf16, swizzled
    __shared__ unsigned Vl[2048];        // [dh64][key64] bf16, swizzled
    __shared__ unsigned Pl[4][512];      // per-wave [q16][key64] bf16, swizzled

    const int q0 = blockIdx.x * 64;
    const int bh = blockIdx.y;
    const int b = bh >> 2, h = bh & 3;
    const int t = threadIdx.x;
    const int w = t >> 6, l = t & 63;
    const int lr = l & 15, lg = l >> 4;
    const float aw = adj_w[0], ab = adj_b[0];

    // Q B-frags (in registers): qrow = q0 + 16w + lr, dh = lg*8 + 32*half + j
    const int qrow = q0 + w * 16 + lr;
    const float* qb = Qp + (size_t)(b * S_LEN + qrow) * HID + h * 64;
    bf16x8 qf[2];
    #pragma unroll
    for (int hh = 0; hh < 2; ++hh) {
        union { unsigned u[4]; bf16x8 v; } tmp;
        #pragma unroll
        for (int jj = 0; jj < 4; ++jj) {
            float x0 = qb[lg * 8 + 32 * hh + 2 * jj];
            float x1 = qb[lg * 8 + 32 * hh + 2 * jj + 1];
            tmp.u[jj] = packbf(x0, x1);
        }
        qf[hh] = tmp.v;
    }

    const unsigned* Kg = reinterpret_cast<const unsigned*>(Kb + (size_t)bh * S_LEN * DH);
    const unsigned* Vg = reinterpret_cast<const unsigned*>(Vt + (size_t)bh * DH * S_LEN);

    float mrow = -1e30f, lrow = 0.f;
    f32x4 o[4] = {};

    for (int k0 = 0; k0 < S_LEN; k0 += 64) {
        __syncthreads();
        // stage K [key][dh] and V^T [dh][key] tiles (bf16 u32 copies, dwordx4)
        #pragma unroll
        for (int i = 0; i < 2; ++i) {
            int id4 = t + i * 256;        // 0..511, 16B units
            int r4 = id4 >> 3, c4 = id4 & 7;
            uint4 kv = *reinterpret_cast<const uint4*>(Kg + (size_t)(k0 + r4) * 32 + c4 * 4);
            *reinterpret_cast<uint4*>((char*)Kl + swz(r4 * 128 + c4 * 16)) = kv;
            uint4 vv = *reinterpret_cast<const uint4*>(Vg + (size_t)r4 * (S_LEN / 2) + (k0 >> 1) + c4 * 4);
            *reinterpret_cast<uint4*>((char*)Vl + swz(r4 * 128 + c4 * 16)) = vv;
        }
        __syncthreads();

        // S^T: 4 key-blocks x (2 dh-halves chained)
        float sv[4][4];
        #pragma unroll
        for (int f = 0; f < 4; ++f) {
            int krow = f * 16 + lr;
            bf16x8 kf0 = *reinterpret_cast<const bf16x8*>(
                (const char*)Kl + swz(krow * 128 + lg * 16));
            bf16x8 kf1 = *reinterpret_cast<const bf16x8*>(
                (const char*)Kl + swz(krow * 128 + lg * 16 + 64));
            f32x4 stf = {0.f, 0.f, 0.f, 0.f};
            stf = __builtin_amdgcn_mfma_f32_16x16x32_bf16(kf0, qf[0], stf, 0, 0, 0);
            stf = __builtin_amdgcn_mfma_f32_16x16x32_bf16(kf1, qf[1], stf, 0, 0, 0);
            // scale + adjacency (adj < 5e-10 for |d|>6 -> skip far tiles)
            int klo = k0 + f * 16;
            bool near = (q0 + w * 16 + 15 >= klo - 6) && (q0 + w * 16 <= klo + 21);
            #pragma unroll
            for (int r = 0; r < 4; ++r) {
                float x = stf[r] * ATT_SCALE;
                if (near) {
                    int key = klo + lg * 4 + r;
                    float dd = (float)(qrow - key);
                    x += __expf(-fabsf(aw * dd * dd - ab));
                }
                sv[f][r] = x;
            }
        }

        // online softmax (per q-row: this lane + lanes lr+16/32/48)
        float tmax = -1e30f;
        #pragma unroll
        for (int f = 0; f < 4; ++f)
            #pragma unroll
            for (int r = 0; r < 4; ++r) tmax = fmaxf(tmax, sv[f][r]);
        tmax = fmaxf(tmax, __shfl_xor(tmax, 16, 64));
        tmax = fmaxf(tmax, __shfl_xor(tmax, 32, 64));
        float mnew = fmaxf(mrow, tmax);
        float fac  = __expf(mrow - mnew);
        float ts = 0.f;
        #pragma unroll
        for (int f = 0; f < 4; ++f)
            #pragma unroll
            for (int r = 0; r < 4; ++r) {
                float p = __expf(sv[f][r] - mnew);
                sv[f][r] = p; ts += p;
            }
        ts += __shfl_xor(ts, 16, 64);
        ts += __shfl_xor(ts, 32, 64);
        lrow = lrow * fac + ts;
        mrow = mnew;
        #pragma unroll
        for (int rf = 0; rf < 4; ++rf) o[rf] *= fac;

        // pack P^T [qrow][key] bf16 into per-wave LDS (lane-local, no barrier)
        #pragma unroll
        for (int f = 0; f < 4; ++f) {
            uint2 pw;
            pw.x = packbf(sv[f][0], sv[f][1]);
            pw.y = packbf(sv[f][2], sv[f][3]);
            *reinterpret_cast<uint2*>((char*)Pl[w] + swz(lr * 128 + f * 32 + lg * 8)) = pw;
        }

        // O^T += V^T @ P^T
        #pragma unroll
        for (int hh = 0; hh < 2; ++hh) {
            bf16x8 pf = *reinterpret_cast<const bf16x8*>(
                (const char*)Pl[w] + swz(lr * 128 + lg * 16 + 64 * hh));
            #pragma unroll
            for (int rf = 0; rf < 4; ++rf) {
                int vrow = rf * 16 + lr;
                bf16x8 vf = *reinterpret_cast<const bf16x8*>(
                    (const char*)Vl + swz(vrow * 128 + lg * 16 + 64 * hh));
                o[rf] = __builtin_amdgcn_mfma_f32_16x16x32_bf16(vf, pf, o[rf], 0, 0, 0);
            }
        }
    }

    const float inv = 1.f / lrow;
    float* gp = glb + ((size_t)(b * S_LEN + qrow) * NH + h) * DH;
    #pragma unroll
    for (int rf = 0; rf < 4; ++rf) {
        float4 ov;
        ov.x = o[rf][0] * inv; ov.y = o[rf][1] * inv;
        ov.z = o[rf][2] * inv; ov.w = o[rf][3] * inv;
        *reinterpret_cast<float4*>(gp + rf * 16 + lg * 4) = ov;
    }
}

// ---------------------------------------------------------------------------
// Local windowed attention (WIN=9, clipped indices dedup'd). fp32.
// ---------------------------------------------------------------------------
__global__ __launch_bounds__(256) void attn_local(
    const float* __restrict__ Qp, const float* __restrict__ Kp,
    const float* __restrict__ Vp, const float* __restrict__ adj_w,
    const float* __restrict__ adj_b, float* __restrict__ lcl)
{
    const int wave = threadIdx.x >> 6;
    const int lane = threadIdx.x & 63;
    const int gr = blockIdx.x * 4 + wave;
    const int b = gr >> 13;
    const int rem = gr & 8191;
    const int h = rem >> 11;
    const int i = rem & 2047;
    const float w = adj_w[0], bb = adj_b[0];

    const float qd = Qp[((size_t)(b * S_LEN + i) * HID) + h * 64 + lane];

    float sc[9]; int cls[9];
    float mx = -1e30f; int prev = -1;
    #pragma unroll
    for (int kk = 0; kk < 9; ++kk) {
        int c = i - 4 + kk;
        c = c < 0 ? 0 : (c > S_LEN - 1 ? S_LEN - 1 : c);
        bool valid = (c != prev);
        prev = c;
        float kd = Kp[((size_t)(b * S_LEN + c) * HID) + h * 64 + lane];
        float part = qd * kd;
        #pragma unroll
        for (int off = 32; off; off >>= 1) part += __shfl_xor(part, off, 64);
        float dd = fabsf((float)(i - c));
        float vv = part * ATT_SCALE + expf(-fabsf(w * dd * dd - bb));
        sc[kk]  = valid ? vv : -1e30f;
        cls[kk] = c;
        mx = fmaxf(mx, sc[kk]);
    }
    float sum = 0.f;
    #pragma unroll
    for (int kk = 0; kk < 9; ++kk) { sc[kk] = expf(sc[kk] - mx); sum += sc[kk]; }
    const float inv = 1.f / sum;
    float o = 0.f;
    #pragma unroll
    for (int kk = 0; kk < 9; ++kk)
        o += sc[kk] * Vp[((size_t)(b * S_LEN + cls[kk]) * HID) + h * 64 + lane];

    lcl[(((size_t)(b * S_LEN + i)) * NH + h) * DH + lane] = o * inv;
}

// ---------------------------------------------------------------------------
__global__ void combine_ss(const float* g, const float* l,
                           const float* alpha, float* out, int n)
{
    const float a = 1.f / (1.f + expf(-alpha[0]));
    for (int idx = blockIdx.x * blockDim.x + threadIdx.x; idx < n;
         idx += gridDim.x * blockDim.x) {
        float x = a * g[idx] + (1.f - a) * l[idx];
        float r = x > 0.f ? sqrtf(x) : (x < 0.f ? -sqrtf(-x) : 0.f);
        out[idx] = r;
    }
}

__global__ __launch_bounds__(256) void colnorm_kernel(
    const float* __restrict__ tmp, float* __restrict__ inv_nrm)
{
    const int bc = blockIdx.x;
    const int b = bc >> 8, c = bc & 255;
    const float* base = tmp + (size_t)b * S_LEN * HID + c;
    float ss = 0.f;
    for (int s = threadIdx.x; s < S_LEN; s += 256) {
        float v = base[(size_t)s * HID];
        ss += v * v;
    }
    #pragma unroll
    for (int off = 32; off; off >>= 1) ss += __shfl_xor(ss, off, 64);
    __shared__ float red[4];
    if ((threadIdx.x & 63) == 0) red[threadIdx.x >> 6] = ss;
    __syncthreads();
    if (threadIdx.x == 0) {
        float t2 = red[0] + red[1] + red[2] + red[3];
        inv_nrm[bc] = 1.f / fmaxf(sqrtf(t2), 1e-12f);
    }
}

__global__ __launch_bounds__(256) void layernorm_k(
    const float* __restrict__ x, const float* __restrict__ g,
    const float* __restrict__ be, float* __restrict__ out)
{
    const int row = blockIdx.x;
    const float4 xv = reinterpret_cast<const float4*>(x + (size_t)row * DMODEL)[threadIdx.x];
    float s  = xv.x + xv.y + xv.z + xv.w;
    float ss = xv.x * xv.x + xv.y * xv.y + xv.z * xv.z + xv.w * xv.w;
    #pragma unroll
    for (int off = 32; off; off >>= 1) {
        s  += __shfl_xor(s,  off, 64);
        ss += __shfl_xor(ss, off, 64);
    }
    __shared__ float rs[4], rss[4];
    if ((threadIdx.x & 63) == 0) { rs[threadIdx.x >> 6] = s; rss[threadIdx.x >> 6] = ss; }
    __syncthreads();
    s  = rs[0] + rs[1] + rs[2] + rs[3];
    ss = rss[0] + rss[1] + rss[2] + rss[3];
    const float mu  = s * (1.f / DMODEL);
    const float var = ss * (1.f / DMODEL) - mu * mu;
    const float r   = rsqrtf(var + LN_EPS);
    const float4 gv = reinterpret_cast<const float4*>(g)[threadIdx.x];
    const float4 bv = reinterpret_cast<const float4*>(be)[threadIdx.x];
    float4 ov;
    ov.x = (xv.x - mu) * r * gv.x + bv.x;
    ov.y = (xv.y - mu) * r * gv.y + bv.y;
    ov.z = (xv.z - mu) * r * gv.z + bv.z;
    ov.w = (xv.w - mu) * r * gv.w + bv.w;
    reinterpret_cast<float4*>(out + (size_t)row * DMODEL)[threadIdx.x] = ov;
}

// ---------------------------------------------------------------------------
extern "C" void kernel_launch(void* const* d_in, const int* in_sizes, int n_in,
                              void* d_out, int out_size, void* d_ws, size_t ws_size,
                              hipStream_t stream)
{
    const float* q     = (const float*)d_in[0];
    const float* k     = (const float*)d_in[1];
    const float* v     = (const float*)d_in[2];
    const float* Wq    = (const float*)d_in[3];
    const float* bq    = (const float*)d_in[4];
    const float* Wk    = (const float*)d_in[5];
    const float* bk    = (const float*)d_in[6];
    const float* Wv    = (const float*)d_in[7];
    const float* bv    = (const float*)d_in[8];
    const float* Wo    = (const float*)d_in[9];
    const float* bo    = (const float*)d_in[10];
    const float* alpha = (const float*)d_in[11];
    const float* adj_w = (const float*)d_in[12];
    const float* adj_b = (const float*)d_in[13];
    const float* W1    = (const float*)d_in[14];
    const float* b1    = (const float*)d_in[15];
    const float* W2    = (const float*)d_in[16];
    const float* b2    = (const float*)d_in[17];
    const float* g1    = (const float*)d_in[18];
    const float* be1   = (const float*)d_in[19];
    const float* g2    = (const float*)d_in[20];
    const float* be2   = (const float*)d_in[21];

    const int ROWS = B_SZ * S_LEN;          // 4096
    const size_t PROJ = (size_t)ROWS * HID; // 1,048,576 floats

    float* ws = (float*)d_ws;
    float* Qp      = ws;
    float* Kp      = Qp + PROJ;
    float* Vp      = Kp + PROJ;
    float* lcl     = Vp + PROJ;
    float* glb     = lcl + PROJ;
    float* inv_nrm = glb + PROJ;                    // 512
    float* x_ln    = inv_nrm + 512;                 // ROWS*DMODEL
    float* hbuf    = x_ln + (size_t)ROWS * DMODEL;  // ROWS*DFF
    float* x1      = Qp;  // alias Qp..lcl = ROWS*DMODEL floats

    // Kb/Vt bf16 alias onto x_ln region (only live before LN1 writes x_ln)
    unsigned short* Kb = (unsigned short*)x_ln;                  // 8*2048*64
    unsigned short* Vt = Kb + (size_t)B_SZ * NH * S_LEN * DH;    // 8*64*2048

    dim3 blk(256);

    // QKV projections (one launch, z selects q/k/v)
    gemm_qkv<<<dim3(32, 2, 3), blk, 0, stream>>>(q, k, v, Wq, Wk, Wv, bq, bk, bv, Qp, Kp, Vp);

    // K/V bf16 prep (Kb row-major, Vt transposed)
    prep_kv<<<dim3(32, 8), blk, 0, stream>>>(Kp, Vp, Kb, Vt);

    // attention
    attn_global_mfma<<<dim3(32, 8), blk, 0, stream>>>(Qp, Kb, Vt, adj_w, adj_b, glb);
    attn_local<<<dim3(B_SZ * NH * S_LEN / 4), blk, 0, stream>>>(Qp, Kp, Vp, adj_w, adj_b, lcl);

    // combine + signed sqrt (in-place over glb)
    combine_ss<<<dim3(1024), blk, 0, stream>>>(glb, lcl, alpha, glb, (int)PROJ);

    // L2 norm over sequence axis
    colnorm_kernel<<<dim3(B_SZ * HID), blk, 0, stream>>>(glb, inv_nrm);

    // attn_out = (tmp/nrm) @ Wo + bo + q
    gemm_mfma<<<dim3(32, 8), blk, 0, stream>>>(glb, Wo, bo, q, inv_nrm, x1, DMODEL, HID, 0);

    // LN1 (overwrites Kb/Vt region — attention is done with them)
    layernorm_k<<<dim3(ROWS), blk, 0, stream>>>(x1, g1, be1, x_ln);

    // FFN
    gemm_mfma<<<dim3(32, 4), blk, 0, stream>>>(x_ln, W1, b1, nullptr, nullptr, hbuf, DFF, DMODEL, 1);
    gemm_mfma<<<dim3(32, 8), blk, 0, stream>>>(hbuf, W2, b2, x_ln, nullptr, x1, DMODEL, DFF, 0);

    // LN2 -> output
    layernorm_k<<<dim3(ROWS), blk, 0, stream>>>(x1, g2, be2, (float*)d_out);
}

// Round 4
// 323.018 us; speedup vs baseline: 3.4768x; 1.3220x over previous
//
#include <hip/hip_runtime.h>

// Problem constants
#define B_SZ   2
#define S_LEN  2048
#define DMODEL 1024
#define HID    256
#define NH     4
#define DH     64
#define DFF    512
#define LN_EPS 1e-5f
#define ATT_SCALE 0.0625f   // 1/sqrt(HID)

typedef __attribute__((ext_vector_type(8))) short bf16x8;
typedef __attribute__((ext_vector_type(4))) float f32x4;

// fp32 -> bf16 RNE
static __device__ __forceinline__ unsigned short f2bf(float x) {
    union { float f; unsigned u; } v; v.f = x;
    unsigned r = v.u + 0x7FFFu + ((v.u >> 16) & 1u);
    return (unsigned short)(r >> 16);
}
static __device__ __forceinline__ unsigned packbf(float a, float b) {
    return (unsigned)f2bf(a) | ((unsigned)f2bf(b) << 16);
}
static __device__ __forceinline__ float bf2f(unsigned short h) {
    union { unsigned u; float f; } v; v.u = ((unsigned)h) << 16; return v.f;
}
// attn-kernel LDS swizzle (bits 4-6 ^= bits 7-9), involution
static __device__ __forceinline__ int swz(int byte) {
    return byte ^ ((byte >> 3) & 0x70);
}

#if defined(__has_builtin)
#if __has_builtin(__builtin_amdgcn_global_load_lds)
#define HAVE_GLD 1
#endif
#endif

// async global->LDS, 16B per lane, LDS dest = uniform base + lane*16
static __device__ __forceinline__ void gld16(const void* g, void* l) {
#ifdef HAVE_GLD
    __builtin_amdgcn_global_load_lds(
        (const __attribute__((address_space(1))) void*)g,
        (__attribute__((address_space(3))) void*)l, 16, 0, 0);
#else
    *(uint4*)((char*)l + (threadIdx.x & 63) * 16) = *(const uint4*)g;
#endif
}

// ---------------------------------------------------------------------------
// bf16 GEMM: 64x64 tile, 1 wave/block, BK=64, double-buffered, 2-phase.
// A [M][K] bf16 row-major, W [N][K] bf16 (pre-transposed weights).
// LDS tiles [64 rows][64 k] bf16 = 128B rows; XOR-swizzle ((row&7)<<4)
// applied via pre-swizzled GLOBAL source (linear gload_lds dest) and on
// the ds_read side.
// ---------------------------------------------------------------------------
__device__ __forceinline__ void gstage(const unsigned short* __restrict__ G,
                                       int row0, int k0, int K, char* lds, int lane)
{
    #pragma unroll
    for (int j = 0; j < 8; ++j) {
        int o = (j * 64 + lane) * 16;          // linear LDS byte offset
        int L = o ^ ((o >> 3) & 0x70);         // swizzled logical offset
        const char* ga = (const char*)G +
            ((size_t)(row0 + (L >> 7)) * K + k0) * 2 + (L & 127);
        gld16(ga, lds + j * 1024);
    }
}

__device__ __forceinline__ void gcompute(const char* As, const char* Bs,
                                         f32x4 acc[4][4], int lr, int lg)
{
    #pragma unroll
    for (int ks = 0; ks < 2; ++ks) {
        bf16x8 af[4], bfv[4];
        #pragma unroll
        for (int m = 0; m < 4; ++m) {
            int r = m * 16 + lr;
            af[m] = *(const bf16x8*)(As + ((r * 128 + ks * 64 + lg * 16) ^ ((lr & 7) << 4)));
        }
        #pragma unroll
        for (int n = 0; n < 4; ++n) {
            int r = n * 16 + lr;
            bfv[n] = *(const bf16x8*)(Bs + ((r * 128 + ks * 64 + lg * 16) ^ ((lr & 7) << 4)));
        }
        #pragma unroll
        for (int m = 0; m < 4; ++m)
            #pragma unroll
            for (int n = 0; n < 4; ++n)
                acc[m][n] = __builtin_amdgcn_mfma_f32_16x16x32_bf16(
                    af[m], bfv[n], acc[m][n], 0, 0, 0);
    }
}

__device__ __forceinline__ void gemm64_core(
    const unsigned short* __restrict__ A, const unsigned short* __restrict__ W,
    const float* __restrict__ bias, const float* __restrict__ residf,
    const unsigned short* __restrict__ residb,
    float* __restrict__ Cf, unsigned short* __restrict__ Cb,
    int N, int K, int relu, int row0, int col0)
{
    __shared__ char As0[8192], As1[8192], Bs0[8192], Bs1[8192];
    const int lane = threadIdx.x;
    const int lr = lane & 15, lg = lane >> 4;

    f32x4 acc[4][4] = {};

    gstage(A, row0, 0, K, As0, lane);
    gstage(W, col0, 0, K, Bs0, lane);
    const int NK = K >> 6;                       // K/64, always even here
    for (int ks = 0; ks + 2 < NK; ks += 2) {
        gstage(A, row0, (ks + 1) * 64, K, As1, lane);
        gstage(W, col0, (ks + 1) * 64, K, Bs1, lane);
        gcompute(As0, Bs0, acc, lr, lg);
        gstage(A, row0, (ks + 2) * 64, K, As0, lane);
        gstage(W, col0, (ks + 2) * 64, K, Bs0, lane);
        gcompute(As1, Bs1, acc, lr, lg);
    }
    gstage(A, row0, (NK - 1) * 64, K, As1, lane);
    gstage(W, col0, (NK - 1) * 64, K, Bs1, lane);
    gcompute(As0, Bs0, acc, lr, lg);
    gcompute(As1, Bs1, acc, lr, lg);

    // epilogue: row = mf*16 + lg*4 + r, col = nf*16 + lr (verified layout)
    #pragma unroll
    for (int mf = 0; mf < 4; ++mf) {
        #pragma unroll
        for (int nf = 0; nf < 4; ++nf) {
            #pragma unroll
            for (int r = 0; r < 4; ++r) {
                int row = row0 + mf * 16 + lg * 4 + r;
                int col = col0 + nf * 16 + lr;
                float v2 = acc[mf][nf][r] + bias[col];
                if (residf) v2 += residf[(size_t)row * N + col];
                if (residb) v2 += bf2f(residb[(size_t)row * N + col]);
                if (relu)   v2 = fmaxf(v2, 0.f);
                if (Cb) Cb[(size_t)row * N + col] = f2bf(v2);
                else    Cf[(size_t)row * N + col] = v2;
            }
        }
    }
}

__global__ __launch_bounds__(64) void gemm_b16(
    const unsigned short* __restrict__ A, const unsigned short* __restrict__ W,
    const float* __restrict__ bias, const float* __restrict__ residf,
    const unsigned short* __restrict__ residb,
    float* __restrict__ Cf, unsigned short* __restrict__ Cb,
    int N, int K, int relu)
{
    gemm64_core(A, W, bias, residf, residb, Cf, Cb, N, K, relu,
                blockIdx.x * 64, blockIdx.y * 64);
}

__global__ __launch_bounds__(64) void gemm_qkv3(
    const unsigned short* __restrict__ qkvb, const unsigned short* __restrict__ Wt,
    const float* __restrict__ bq, const float* __restrict__ bk,
    const float* __restrict__ bv, unsigned short* __restrict__ outb)
{
    const int z = blockIdx.z;
    const unsigned short* A = qkvb + (size_t)z * 4096 * 1024;
    const unsigned short* W = Wt + (size_t)z * 262144;
    const float* bias = (z == 0) ? bq : ((z == 1) ? bk : bv);
    unsigned short* Cb = outb + (size_t)z * 4096 * 256;
    gemm64_core(A, W, bias, nullptr, nullptr, nullptr, Cb, 256, 1024, 0,
                blockIdx.x * 64, blockIdx.y * 64);
}

// ---------------------------------------------------------------------------
// Weight prep: fp32 [K][N] -> bf16 [N][K], all 6 weights in one launch.
// grid 512 blocks of 256.
// ---------------------------------------------------------------------------
__global__ __launch_bounds__(256) void prep_w(
    const float* __restrict__ Wq, const float* __restrict__ Wk,
    const float* __restrict__ Wv, const float* __restrict__ Wo,
    const float* __restrict__ W1, const float* __restrict__ W2,
    unsigned short* __restrict__ Wt)
{
    __shared__ float tile[64][65];
    const int bid = blockIdx.x;
    const float* src; int K, N; size_t off; int local;
    if (bid < 64)       { src = Wq; K = 1024; N = 256;  off = 0;        local = bid; }
    else if (bid < 128) { src = Wk; K = 1024; N = 256;  off = 262144;  local = bid - 64; }
    else if (bid < 192) { src = Wv; K = 1024; N = 256;  off = 524288;  local = bid - 128; }
    else if (bid < 256) { src = Wo; K = 256;  N = 1024; off = 786432;  local = bid - 192; }
    else if (bid < 384) { src = W1; K = 1024; N = 512;  off = 1048576; local = bid - 256; }
    else                { src = W2; K = 512;  N = 1024; off = 1572864; local = bid - 384; }
    const int nkt = K >> 6;
    const int k0 = (local % nkt) * 64, n0 = (local / nkt) * 64;
    const int t = threadIdx.x;
    #pragma unroll
    for (int i = 0; i < 16; ++i) {
        int id = t + i * 256;
        int r = id >> 6, c = id & 63;
        tile[r][c] = src[(size_t)(k0 + r) * N + n0 + c];
    }
    __syncthreads();
    unsigned* Wt32 = (unsigned*)(Wt + off);
    #pragma unroll
    for (int i = 0; i < 8; ++i) {
        int id = t + i * 256;
        int n = id >> 5, ku = id & 31;
        Wt32[((size_t)(n0 + n) * K + k0) / 2 + ku] =
            packbf(tile[2 * ku][n], tile[2 * ku + 1][n]);
    }
}

// q,k,v fp32 -> bf16 contiguous [3][4096][1024]
__global__ __launch_bounds__(256) void prep_qkv(
    const float* __restrict__ q, const float* __restrict__ k,
    const float* __restrict__ v, unsigned short* __restrict__ qkvb)
{
    const float* src = blockIdx.z == 0 ? q : (blockIdx.z == 1 ? k : v);
    uint2* dst = (uint2*)(qkvb + (size_t)blockIdx.z * 4096 * 1024);
    int idx = blockIdx.x * 256 + threadIdx.x;          // float4 units, 1M per tensor
    float4 x = ((const float4*)src)[idx];
    dst[idx] = make_uint2(packbf(x.x, x.y), packbf(x.z, x.w));
}

// Vb [b][s][h*64+d] bf16 -> Vt [bh][d][s] bf16
__global__ __launch_bounds__(256) void prep_v(const unsigned short* __restrict__ Vb,
                                              unsigned short* __restrict__ Vt)
{
    __shared__ unsigned Vl[64][34];
    const int k0 = blockIdx.x * 64;
    const int bh = blockIdx.y;
    const int b = bh >> 2, h = bh & 3;
    const int t = threadIdx.x;
    const unsigned* Vg = (const unsigned*)Vb + (size_t)(b * S_LEN) * 128 + h * 32;
    #pragma unroll
    for (int i = 0; i < 8; ++i) {
        int id = t + i * 256;
        int key = id >> 5, cu = id & 31;
        Vl[key][cu] = Vg[(size_t)(k0 + key) * 128 + cu];
    }
    __syncthreads();
    const unsigned short* Vl16 = (const unsigned short*)Vl;
    unsigned* Vo = (unsigned*)Vt + (size_t)bh * 65536;
    #pragma unroll
    for (int i = 0; i < 8; ++i) {
        int id = t + i * 256;
        int d = id >> 5, ku = id & 31;
        unsigned lo = Vl16[(2 * ku) * 68 + d];
        unsigned hi = Vl16[(2 * ku + 1) * 68 + d];
        Vo[(size_t)d * 1024 + (k0 >> 1) + ku] = lo | (hi << 16);
    }
}

// ---------------------------------------------------------------------------
// Global attention, MFMA flash. grid (S/64, B*NH), 256 thr = 4 waves.
// ---------------------------------------------------------------------------
__global__ __launch_bounds__(256) void attn_global_mfma(
    const unsigned short* __restrict__ Qb, const unsigned short* __restrict__ Kb,
    const unsigned short* __restrict__ Vt, const float* __restrict__ adj_w,
    const float* __restrict__ adj_b, unsigned short* __restrict__ glb_b)
{
    __shared__ unsigned Kl[2048];        // [key64][dh64] bf16, swizzled
    __shared__ unsigned Vl[2048];        // [dh64][key64] bf16, swizzled
    __shared__ unsigned Pl[4][512];      // per-wave [q16][key64] bf16, swizzled

    const int q0 = blockIdx.x * 64;
    const int bh = blockIdx.y;
    const int b = bh >> 2, h = bh & 3;
    const int t = threadIdx.x;
    const int w = t >> 6, l = t & 63;
    const int lr = l & 15, lg = l >> 4;
    const float aw = adj_w[0], ab = adj_b[0];

    const int qrow = q0 + w * 16 + lr;
    const unsigned* qb32 = (const unsigned*)Qb + (size_t)(b * S_LEN + qrow) * 128 + h * 32;
    bf16x8 qf[2];
    #pragma unroll
    for (int hh = 0; hh < 2; ++hh) {
        union { unsigned u[4]; bf16x8 v; } tmpu;
        #pragma unroll
        for (int jj = 0; jj < 4; ++jj) tmpu.u[jj] = qb32[hh * 16 + lg * 4 + jj];
        qf[hh] = tmpu.v;
    }

    const unsigned* Kg = (const unsigned*)Kb + (size_t)(b * S_LEN) * 128 + h * 32;
    const unsigned* Vg = (const unsigned*)Vt + (size_t)bh * 65536;

    float mrow = -1e30f, lrow = 0.f;
    f32x4 o[4] = {};

    for (int k0 = 0; k0 < S_LEN; k0 += 64) {
        __syncthreads();
        #pragma unroll
        for (int i = 0; i < 2; ++i) {
            int id4 = t + i * 256;
            int r4 = id4 >> 3, c4 = id4 & 7;
            uint4 kv = *(const uint4*)(Kg + (size_t)(k0 + r4) * 128 + c4 * 4);
            *(uint4*)((char*)Kl + swz(r4 * 128 + c4 * 16)) = kv;
            uint4 vv = *(const uint4*)(Vg + (size_t)r4 * 1024 + (k0 >> 1) + c4 * 4);
            *(uint4*)((char*)Vl + swz(r4 * 128 + c4 * 16)) = vv;
        }
        __syncthreads();

        float sv[4][4];
        #pragma unroll
        for (int f = 0; f < 4; ++f) {
            int krow = f * 16 + lr;
            bf16x8 kf0 = *(const bf16x8*)((const char*)Kl + swz(krow * 128 + lg * 16));
            bf16x8 kf1 = *(const bf16x8*)((const char*)Kl + swz(krow * 128 + lg * 16 + 64));
            f32x4 stf = {0.f, 0.f, 0.f, 0.f};
            stf = __builtin_amdgcn_mfma_f32_16x16x32_bf16(kf0, qf[0], stf, 0, 0, 0);
            stf = __builtin_amdgcn_mfma_f32_16x16x32_bf16(kf1, qf[1], stf, 0, 0, 0);
            int klo = k0 + f * 16;
            bool near = (q0 + w * 16 + 15 >= klo - 6) && (q0 + w * 16 <= klo + 21);
            #pragma unroll
            for (int r = 0; r < 4; ++r) {
                float x = stf[r] * ATT_SCALE;
                if (near) {
                    int key = klo + lg * 4 + r;
                    float dd = (float)(qrow - key);
                    x += __expf(-fabsf(aw * dd * dd - ab));
                }
                sv[f][r] = x;
            }
        }

        float tmax = -1e30f;
        #pragma unroll
        for (int f = 0; f < 4; ++f)
            #pragma unroll
            for (int r = 0; r < 4; ++r) tmax = fmaxf(tmax, sv[f][r]);
        tmax = fmaxf(tmax, __shfl_xor(tmax, 16, 64));
        tmax = fmaxf(tmax, __shfl_xor(tmax, 32, 64));
        float mnew = fmaxf(mrow, tmax);
        float fac  = __expf(mrow - mnew);
        float ts = 0.f;
        #pragma unroll
        for (int f = 0; f < 4; ++f)
            #pragma unroll
            for (int r = 0; r < 4; ++r) {
                float p = __expf(sv[f][r] - mnew);
                sv[f][r] = p; ts += p;
            }
        ts += __shfl_xor(ts, 16, 64);
        ts += __shfl_xor(ts, 32, 64);
        lrow = lrow * fac + ts;
        mrow = mnew;
        #pragma unroll
        for (int rf = 0; rf < 4; ++rf) o[rf] *= fac;

        #pragma unroll
        for (int f = 0; f < 4; ++f) {
            uint2 pw;
            pw.x = packbf(sv[f][0], sv[f][1]);
            pw.y = packbf(sv[f][2], sv[f][3]);
            *(uint2*)((char*)Pl[w] + swz(lr * 128 + f * 32 + lg * 8)) = pw;
        }

        #pragma unroll
        for (int hh = 0; hh < 2; ++hh) {
            bf16x8 pf = *(const bf16x8*)((const char*)Pl[w] + swz(lr * 128 + lg * 16 + 64 * hh));
            #pragma unroll
            for (int rf = 0; rf < 4; ++rf) {
                int vrow = rf * 16 + lr;
                bf16x8 vf = *(const bf16x8*)((const char*)Vl + swz(vrow * 128 + lg * 16 + 64 * hh));
                o[rf] = __builtin_amdgcn_mfma_f32_16x16x32_bf16(vf, pf, o[rf], 0, 0, 0);
            }
        }
    }

    const float inv = 1.f / lrow;
    unsigned* gp = (unsigned*)glb_b + (((size_t)(b * S_LEN + qrow)) * NH + h) * 32;
    #pragma unroll
    for (int rf = 0; rf < 4; ++rf) {
        gp[(rf * 16 + lg * 4) >> 1]       = packbf(o[rf][0] * inv, o[rf][1] * inv);
        gp[((rf * 16 + lg * 4) >> 1) + 1] = packbf(o[rf][2] * inv, o[rf][3] * inv);
    }
}

// ---------------------------------------------------------------------------
// Local windowed attention (WIN=9, clipped indices dedup'd), bf16 in/out.
// ---------------------------------------------------------------------------
__global__ __launch_bounds__(256) void attn_local(
    const unsigned short* __restrict__ Qb, const unsigned short* __restrict__ Kb,
    const unsigned short* __restrict__ Vb, const float* __restrict__ adj_w,
    const float* __restrict__ adj_b, unsigned short* __restrict__ lcl_b)
{
    const int wave = threadIdx.x >> 6;
    const int lane = threadIdx.x & 63;
    const int gr = blockIdx.x * 4 + wave;
    const int b = gr >> 13;
    const int rem = gr & 8191;
    const int h = rem >> 11;
    const int i = rem & 2047;
    const float w = adj_w[0], bb = adj_b[0];

    const float qd = bf2f(Qb[(size_t)(b * S_LEN + i) * HID + h * 64 + lane]);

    float sc[9]; int cls[9];
    float mx = -1e30f; int prev = -1;
    #pragma unroll
    for (int kk = 0; kk < 9; ++kk) {
        int c = i - 4 + kk;
        c = c < 0 ? 0 : (c > S_LEN - 1 ? S_LEN - 1 : c);
        bool valid = (c != prev);
        prev = c;
        float kd = bf2f(Kb[(size_t)(b * S_LEN + c) * HID + h * 64 + lane]);
        float part = qd * kd;
        #pragma unroll
        for (int off = 32; off; off >>= 1) part += __shfl_xor(part, off, 64);
        float dd = fabsf((float)(i - c));
        float vv = part * ATT_SCALE + expf(-fabsf(w * dd * dd - bb));
        sc[kk]  = valid ? vv : -1e30f;
        cls[kk] = c;
        mx = fmaxf(mx, sc[kk]);
    }
    float sum = 0.f;
    #pragma unroll
    for (int kk = 0; kk < 9; ++kk) { sc[kk] = expf(sc[kk] - mx); sum += sc[kk]; }
    const float inv = 1.f / sum;
    float o = 0.f;
    #pragma unroll
    for (int kk = 0; kk < 9; ++kk)
        o += sc[kk] * bf2f(Vb[(size_t)(b * S_LEN + cls[kk]) * HID + h * 64 + lane]);

    lcl_b[((size_t)(b * S_LEN + i)) * HID + h * 64 + lane] = f2bf(o * inv);
}

// ---------------------------------------------------------------------------
__global__ __launch_bounds__(256) void combine_ss(
    const unsigned short* __restrict__ g, const unsigned short* __restrict__ l,
    const float* __restrict__ alpha, unsigned short* __restrict__ out)
{
    const float a = 1.f / (1.f + expf(-alpha[0]));
    int idx = blockIdx.x * 256 + threadIdx.x;
    float x = a * bf2f(g[idx]) + (1.f - a) * bf2f(l[idx]);
    float r = x > 0.f ? sqrtf(x) : (x < 0.f ? -sqrtf(-x) : 0.f);
    out[idx] = f2bf(r);
}

// partial column sums of squares: grid 32 = (b, s-chunk of 128), 256 thr = c
__global__ __launch_bounds__(256) void colnorm_part(
    const unsigned short* __restrict__ tmpb, float* __restrict__ part)
{
    const int b = blockIdx.x >> 4, ch = blockIdx.x & 15;
    const int s0 = ch * 128;
    const unsigned short* base = tmpb + ((size_t)b * S_LEN + s0) * HID + threadIdx.x;
    float ss = 0.f;
    #pragma unroll 4
    for (int s = 0; s < 128; ++s) {
        float v2 = bf2f(base[(size_t)s * HID]);
        ss += v2 * v2;
    }
    part[blockIdx.x * 256 + threadIdx.x] = ss;
}

__global__ void colnorm_fin(const float* __restrict__ part, float* __restrict__ inv_nrm)
{
    const int tid = threadIdx.x;          // 512 = b*256+c
    const int b = tid >> 8, c = tid & 255;
    float s = 0.f;
    #pragma unroll
    for (int ch = 0; ch < 16; ++ch) s += part[(b * 16 + ch) * 256 + c];
    inv_nrm[tid] = 1.f / fmaxf(sqrtf(s), 1e-12f);
}

__global__ __launch_bounds__(256) void scale_inv(
    unsigned short* __restrict__ tmpb, const float* __restrict__ inv_nrm)
{
    int idx = blockIdx.x * 256 + threadIdx.x;
    int c = idx & 255, b = idx >> 19;
    tmpb[idx] = f2bf(bf2f(tmpb[idx]) * inv_nrm[b * 256 + c]);
}

// ---------------------------------------------------------------------------
// LayerNorm over last dim (1024). Optional fp32 and/or bf16 outputs.
// ---------------------------------------------------------------------------
__global__ __launch_bounds__(256) void layernorm_k(
    const float* __restrict__ x, const float* __restrict__ g,
    const float* __restrict__ be, float* __restrict__ outf,
    unsigned short* __restrict__ outb)
{
    const int row = blockIdx.x;
    const float4 xv = ((const float4*)(x + (size_t)row * DMODEL))[threadIdx.x];
    float s  = xv.x + xv.y + xv.z + xv.w;
    float ss = xv.x * xv.x + xv.y * xv.y + xv.z * xv.z + xv.w * xv.w;
    #pragma unroll
    for (int off = 32; off; off >>= 1) {
        s  += __shfl_xor(s,  off, 64);
        ss += __shfl_xor(ss, off, 64);
    }
    __shared__ float rs[4], rss[4];
    if ((threadIdx.x & 63) == 0) { rs[threadIdx.x >> 6] = s; rss[threadIdx.x >> 6] = ss; }
    __syncthreads();
    s  = rs[0] + rs[1] + rs[2] + rs[3];
    ss = rss[0] + rss[1] + rss[2] + rss[3];
    const float mu  = s * (1.f / DMODEL);
    const float var = ss * (1.f / DMODEL) - mu * mu;
    const float r   = rsqrtf(var + LN_EPS);
    const float4 gv = ((const float4*)g)[threadIdx.x];
    const float4 bv = ((const float4*)be)[threadIdx.x];
    float4 ov;
    ov.x = (xv.x - mu) * r * gv.x + bv.x;
    ov.y = (xv.y - mu) * r * gv.y + bv.y;
    ov.z = (xv.z - mu) * r * gv.z + bv.z;
    ov.w = (xv.w - mu) * r * gv.w + bv.w;
    if (outf) ((float4*)(outf + (size_t)row * DMODEL))[threadIdx.x] = ov;
    if (outb) {
        unsigned* ob = (unsigned*)(outb + (size_t)row * DMODEL);
        ob[threadIdx.x * 2]     = packbf(ov.x, ov.y);
        ob[threadIdx.x * 2 + 1] = packbf(ov.z, ov.w);
    }
}

// ---------------------------------------------------------------------------
extern "C" void kernel_launch(void* const* d_in, const int* in_sizes, int n_in,
                              void* d_out, int out_size, void* d_ws, size_t ws_size,
                              hipStream_t stream)
{
    const float* q     = (const float*)d_in[0];
    const float* k     = (const float*)d_in[1];
    const float* v     = (const float*)d_in[2];
    const float* Wq    = (const float*)d_in[3];
    const float* bq    = (const float*)d_in[4];
    const float* Wk    = (const float*)d_in[5];
    const float* bk    = (const float*)d_in[6];
    const float* Wv    = (const float*)d_in[7];
    const float* bv    = (const float*)d_in[8];
    const float* Wo    = (const float*)d_in[9];
    const float* bo    = (const float*)d_in[10];
    const float* alpha = (const float*)d_in[11];
    const float* adj_w = (const float*)d_in[12];
    const float* adj_b = (const float*)d_in[13];
    const float* W1    = (const float*)d_in[14];
    const float* b1    = (const float*)d_in[15];
    const float* W2    = (const float*)d_in[16];
    const float* b2    = (const float*)d_in[17];
    const float* g1    = (const float*)d_in[18];
    const float* be1   = (const float*)d_in[19];
    const float* g2    = (const float*)d_in[20];
    const float* be2   = (const float*)d_in[21];

    const int ROWS = B_SZ * S_LEN;     // 4096

    // Workspace layout (bytes), max 43MB:
    char* WS = (char*)d_ws;
    float*          x1     = (float*)WS;                                 // [0,16MB)
    unsigned short* xlnb   = (unsigned short*)(WS + (16u << 20));        // [16,24)
    unsigned short* glb_b  = (unsigned short*)(WS + (24u << 20));        // [24,26)
    unsigned short* lcl_b  = (unsigned short*)(WS + (26u << 20));        // [26,28)
    unsigned short* Qb     = (unsigned short*)(WS + (28u << 20));        // [28,30)
    unsigned short* Kb     = (unsigned short*)(WS + (30u << 20));        // [30,32)
    unsigned short* Vb     = (unsigned short*)(WS + (32u << 20));        // [32,34)
    unsigned short* Vt     = (unsigned short*)(WS + (34u << 20));        // [34,36)
    unsigned short* tmpb   = (unsigned short*)(WS + (36u << 20));        // [36,38)
    float*          invn   = (float*)(WS + (38u << 20));                 // 2KB
    float*          part   = (float*)(WS + (38u << 20) + 8192);          // 32KB
    unsigned short* Wt     = (unsigned short*)(WS + (39u << 20));        // [39,43)
    unsigned short* hbufb  = (unsigned short*)(WS + (28u << 20));        // alias Qb/Kb
    unsigned short* qkvb   = (unsigned short*)WS;                        // alias [0,24)

    // 1. weight transpose + bf16
    prep_w<<<dim3(512), dim3(256), 0, stream>>>(Wq, Wk, Wv, Wo, W1, W2, Wt);
    // 2. q,k,v -> bf16
    prep_qkv<<<dim3(4096, 1, 3), dim3(256), 0, stream>>>(q, k, v, qkvb);
    // 3. QKV projections -> Qb/Kb/Vb bf16
    gemm_qkv3<<<dim3(64, 4, 3), dim3(64), 0, stream>>>(qkvb, Wt, bq, bk, bv, Qb);
    // 4. V transpose
    prep_v<<<dim3(32, 8), dim3(256), 0, stream>>>(Vb, Vt);
    // 5. attention
    attn_global_mfma<<<dim3(32, 8), dim3(256), 0, stream>>>(Qb, Kb, Vt, adj_w, adj_b, glb_b);
    attn_local<<<dim3(4096), dim3(256), 0, stream>>>(Qb, Kb, Vb, adj_w, adj_b, lcl_b);
    // 6. combine + signed sqrt -> tmpb
    combine_ss<<<dim3(4096), dim3(256), 0, stream>>>(glb_b, lcl_b, alpha, tmpb);
    // 7. L2 norm over sequence axis
    colnorm_part<<<dim3(32), dim3(256), 0, stream>>>(tmpb, part);
    colnorm_fin<<<dim3(1), dim3(512), 0, stream>>>(part, invn);
    scale_inv<<<dim3(4096), dim3(256), 0, stream>>>(tmpb, invn);
    // 8. attn_out = tmpb @ Wo + bo + q -> x1 (fp32)
    gemm_b16<<<dim3(64, 16), dim3(64), 0, stream>>>(tmpb, Wt + 786432, bo, q, nullptr,
                                                    x1, nullptr, DMODEL, HID, 0);
    // 9. LN1 -> xlnb (bf16)
    layernorm_k<<<dim3(ROWS), dim3(256), 0, stream>>>(x1, g1, be1, nullptr, xlnb);
    // 10. FFN1 -> hbufb (bf16, relu)
    gemm_b16<<<dim3(64, 8), dim3(64), 0, stream>>>(xlnb, Wt + 1048576, b1, nullptr, nullptr,
                                                   nullptr, hbufb, DFF, DMODEL, 1);
    // 11. FFN2 + resid xlnb -> x1 (fp32)
    gemm_b16<<<dim3(64, 16), dim3(64), 0, stream>>>(hbufb, Wt + 1572864, b2, nullptr, xlnb,
                                                    x1, nullptr, DMODEL, DFF, 0);
    // 12. LN2 -> output
    layernorm_k<<<dim3(ROWS), dim3(256), 0, stream>>>(x1, g2, be2, (float*)d_out, nullptr);
}